// Round 13
// baseline (573.102 us; speedup 1.0000x reference)
//
#include <hip/hip_runtime.h>

typedef unsigned short ushort_t;
typedef unsigned int uint_t;
typedef unsigned char u8_t;

typedef __bf16 bf16x8 __attribute__((ext_vector_type(8)));
typedef _Float16 f16x8 __attribute__((ext_vector_type(8)));
typedef float f32x4 __attribute__((ext_vector_type(4)));
typedef uint_t uint32x4 __attribute__((ext_vector_type(4)));
typedef uint_t uint32x2 __attribute__((ext_vector_type(2)));
typedef _Float16 h2 __attribute__((ext_vector_type(2)));

#define EPB 5120     // edges per build chunk (NBLK=625 -> 2.4 blocks/CU in p1/p3)
#define NSH 9        // bucket = dst >> NSH (512 nodes/bucket, B=196)
                     // R11 lesson: NSH=7 gave 26B scatter runs -> 5.7x write amp.
#define MSK 511      // (1<<NSH)-1
#define BPAD 4104    // per-bucket adj pad slack: 8*512 worst case + 8 align (mult of 8)

// ---------- bf16 helpers (RNE fp32->bf16; bit-shift bf16->fp32) ----------
__device__ __forceinline__ float b2f(ushort_t u) {
    union { uint_t ui; float f; } c; c.ui = ((uint_t)u) << 16; return c.f;
}
__device__ __forceinline__ ushort_t f2b(float f) {
    union { float f; uint_t ui; } c; c.f = f;
    uint_t u = c.ui;
    uint_t r = (u + 0x7fffu + ((u >> 16) & 1u)) >> 16;
    return (ushort_t)r;
}
// fp32 -> fp8 e5m2 (RNE via f16; e5m2 = top byte of f16)
__device__ __forceinline__ u8_t f2e5(float x) {
    ushort_t h = __builtin_bit_cast(ushort_t, (_Float16)x);
    uint_t r = ((uint_t)h + 0x7Fu + ((h >> 8) & 1u)) >> 8;
    return (u8_t)r;
}
// unpack dword of 4 e5m2 bytes into 2 packed-f16 pairs and accumulate
// (e5m2<<8 is an EXACT f16: same exponent bias/width, mantissa zero-extended)
__device__ __forceinline__ void upk_add(uint_t d, h2* acc) {
    uint_t A = __builtin_amdgcn_perm(0u, d, 0x010C000Cu);  // (b0<<8, b1<<8) = two f16
    uint_t B = __builtin_amdgcn_perm(0u, d, 0x030C020Cu);  // (b2<<8, b3<<8)
    acc[0] += __builtin_bit_cast(h2, A);
    acc[1] += __builtin_bit_cast(h2, B);
}

// ---------- P1: per-chunk bucket histogram (LDS atomics only) + weight transpose ----------
// extra blocks: [NBLK, NBLK+128) transpose W1 (bf16) / W2 (f16);
// block NBLK+128 zeroes h8 row N and the pool accumulator gsum.
__global__ __launch_bounds__(256) void p1_hist(const int* __restrict__ dst,
                                               int* __restrict__ H,
                                               const float* __restrict__ W1,
                                               const float* __restrict__ W2,
                                               ushort_t* __restrict__ W1t,
                                               ushort_t* __restrict__ W2t,
                                               u8_t* __restrict__ h8z,
                                               float* __restrict__ gsum,
                                               int E, int NBLK, int B, int N, int G) {
    int t = threadIdx.x, c = blockIdx.x;
    if (c >= NBLK + 128) {                 // zero h8 pad row + pool accumulator
        if (t < 32) ((uint_t*)h8z)[(size_t)N * 32 + t] = 0u;
        for (int i = t; i < G; i += 256) gsum[i] = 0.f;
        return;
    }
    if (c >= NBLK) {
        int idx = (c - NBLK) * 256 + t;   // 0..32767
        int sel = idx >> 14;
        int i = idx & 16383;
        int k = i >> 7, nn = i & 127;
        if (sel) {  // W2 -> f16 bits (layer-2 GEMM uses f16 MFMA vs fp8 A-operand)
            W2t[nn * 128 + k] = __builtin_bit_cast(ushort_t, (_Float16)W2[k * 128 + nn]);
        } else {    // W1 -> bf16 bits
            W1t[nn * 128 + k] = f2b(W1[k * 128 + nn]);
        }
        return;
    }
    __shared__ int hist[256];
    if (t < 256) hist[t] = 0;
    __syncthreads();
    int base = c * EPB;
    int lim = min(E - base, EPB);
    for (int i = t; i < lim; i += 256)
        atomicAdd(&hist[dst[base + i] >> NSH], 1);
    __syncthreads();
    if (t < B) H[t * NBLK + c] = hist[t];
}

// ---------- scan: per-256-chunk sums ----------
__global__ __launch_bounds__(256) void reduce256(const int* __restrict__ in,
                                                 int* __restrict__ bsums, int n) {
    __shared__ int s[256];
    int t = threadIdx.x, g = blockIdx.x * 256 + t;
    s[t] = (g < n) ? in[g] : 0;
    __syncthreads();
    for (int o = 128; o > 0; o >>= 1) {
        if (t < o) s[t] += s[t + o];
        __syncthreads();
    }
    if (t == 0) bsums[blockIdx.x] = s[0];
}

// ---------- scan: single-block exclusive scan (n <= 512) ----------
__global__ __launch_bounds__(512) void scan_small(const int* __restrict__ in,
                                                  int* __restrict__ outEx, int n) {
    __shared__ int s[512];
    int t = threadIdx.x;
    int v = (t < n) ? in[t] : 0;
    s[t] = v;
    __syncthreads();
    for (int o = 1; o < 512; o <<= 1) {
        int x = 0;
        if (t >= o) x = s[t - o];
        __syncthreads();
        s[t] += x;
        __syncthreads();
    }
    if (t < n) outEx[t] = s[t] - v;
}

// ---------- scan: per-chunk exclusive scan + chunk offset ----------
__global__ __launch_bounds__(256) void scan256ex(const int* __restrict__ in,
                                                 const int* __restrict__ boffs,
                                                 int* __restrict__ outEx, int n) {
    __shared__ int s[256];
    int t = threadIdx.x, g = blockIdx.x * 256 + t;
    int v = (g < n) ? in[g] : 0;
    s[t] = v;
    __syncthreads();
    for (int o = 1; o < 256; o <<= 1) {
        int x = 0;
        if (t >= o) x = s[t - o];
        __syncthreads();
        s[t] += x;
        __syncthreads();
    }
    if (g < n) outEx[g] = boffs[blockIdx.x] + s[t] - v;
}

// ---------- P3: partition scatter by dst-bucket (LDS rank) ----------
__global__ __launch_bounds__(256) void p3_scatter(const int* __restrict__ src,
                                                  const int* __restrict__ dst,
                                                  const int* __restrict__ Hex,
                                                  uint_t* __restrict__ packed,
                                                  int E, int NBLK, int B) {
    __shared__ int offsL[256];
    __shared__ int cur[256];
    int t = threadIdx.x, c = blockIdx.x;
    if (t < B) {
        offsL[t] = Hex[t * NBLK + c];
        cur[t] = 0;
    }
    __syncthreads();
    int base = c * EPB;
    int lim = min(E - base, EPB);
    for (int i = t; i < lim; i += 256) {
        int d = dst[base + i];
        int s = src[base + i];
        int b = d >> NSH;
        int r = atomicAdd(&cur[b], 1);
        packed[offsL[b] + r] = ((uint_t)s << NSH) | (uint_t)(d & MSK);
    }
}

// ---------- P4: per-bucket padded CSR build (512 nodes/bucket, streamed twice) ------
__global__ __launch_bounds__(512) void p4_build(const uint_t* __restrict__ packed,
                                                const int* __restrict__ Hex,
                                                int* __restrict__ adj,
                                                int* __restrict__ offs,
                                                int* __restrict__ dgr,
                                                float* __restrict__ dinv,
                                                int E, int N, int NBLK, int B) {
    __shared__ int dcnt[512], loc[512], cur[512], sps[512];
    int t = threadIdx.x, b = blockIdx.x;
    int bs = Hex[b * NBLK];
    int be = (b + 1 < B) ? Hex[(b + 1) * NBLK] : E;
    int m = be - bs;
    dcnt[t] = 0;
    __syncthreads();
    for (int i = t; i < m; i += 512)
        atomicAdd(&dcnt[packed[bs + i] & MSK], 1);
    __syncthreads();
    int d = dcnt[t];
    int pd = (d + 8) & ~7;   // (deg + 1 self) rounded up to 8
    sps[t] = pd;
    __syncthreads();
    for (int o = 1; o < 512; o <<= 1) {   // inclusive scan over 512 padded degrees
        int x = 0;
        if (t >= o) x = sps[t - o];
        __syncthreads();
        sps[t] += x;
        __syncthreads();
    }
    int bsp = ((bs + 7) & ~7) + b * BPAD;   // aligned padded bucket base
    int ex = sps[t] - pd;
    int node = b * 512 + t;
    if (node < N) {
        int nbase = bsp + ex;
        offs[node] = nbase;
        dgr[node]  = pd;
        dinv[node] = rsqrtf((float)(d + 1));
        adj[nbase] = node;                        // self-loop first
        for (int i = d + 1; i < pd; ++i)
            adj[nbase + i] = N;                   // zero-row pads
    }
    loc[t] = ex + 1;   // neighbors start after the self entry
    cur[t] = 0;
    __syncthreads();
    for (int i = t; i < m; i += 512) {
        uint_t p = packed[bs + i];
        int l = p & MSK;
        int r = atomicAdd(&cur[l], 1);
        adj[bsp + loc[l] + r] = (int)(p >> NSH);
    }
}

// ---------- GEMM layer-2 (fp8 e5m2 A in, f16 MFMA): H8 = e5m2((A@W2)*dinv) ----------
// A bytes <<8 are exact f16; B = W2t stored as f16 (MORE precise than the old bf16).
__global__ __launch_bounds__(256, 4) void gemm_scale(const u8_t* __restrict__ Xin8,
                                                     const ushort_t* __restrict__ Wt,
                                                     const float* __restrict__ dinv,
                                                     u8_t* __restrict__ Hout8, int n) {
    __shared__ ushort_t lds[128 * 136];
    int tid = threadIdx.x;
    for (int i = tid; i < 128 * 16; i += 256) {
        int r = i >> 4, c8 = (i & 15) << 3;
        *(uint32x4*)(lds + r * 136 + c8) = *(const uint32x4*)(Wt + r * 128 + c8);
    }
    __syncthreads();
    int lane = tid & 63, wave = tid >> 6;
    int m = lane & 15, q = lane >> 4;
    int row0 = blockIdx.x * 64 + wave * 16;
    int ar = row0 + m;
    if (ar > n - 1) ar = n - 1;
    f16x8 a[4];
#pragma unroll
    for (int ks = 0; ks < 4; ++ks) {
        uint32x2 dv8 = *(const uint32x2*)(Xin8 + (size_t)ar * 128 + ks * 32 + q * 8);
        uint_t tw[4];
        tw[0] = __builtin_amdgcn_perm(0u, dv8[0], 0x010C000Cu);  // (b0,b1) as f16
        tw[1] = __builtin_amdgcn_perm(0u, dv8[0], 0x030C020Cu);  // (b2,b3)
        tw[2] = __builtin_amdgcn_perm(0u, dv8[1], 0x010C000Cu);  // (b4,b5)
        tw[3] = __builtin_amdgcn_perm(0u, dv8[1], 0x030C020Cu);  // (b6,b7)
        a[ks] = __builtin_bit_cast(f16x8, *(uint32x4*)tw);
    }
    f32x4 acc[8];
    f32x4 zero = {0.f, 0.f, 0.f, 0.f};
#pragma unroll
    for (int nt = 0; nt < 8; ++nt) acc[nt] = zero;
#pragma unroll
    for (int nt = 0; nt < 8; ++nt) {
#pragma unroll
        for (int ks = 0; ks < 4; ++ks) {
            f16x8 b = __builtin_bit_cast(f16x8,
                *(const uint32x4*)(lds + (nt * 16 + m) * 136 + ks * 32 + q * 8));
            acc[nt] = __builtin_amdgcn_mfma_f32_16x16x32_f16(a[ks], b, acc[nt], 0, 0, 0);
        }
    }
    float dv[4];
#pragma unroll
    for (int r = 0; r < 4; ++r) {
        int gr = row0 + q * 4 + r;
        dv[r] = (gr < n) ? dinv[gr] : 0.f;
    }
#pragma unroll
    for (int nt = 0; nt < 8; ++nt) {
#pragma unroll
        for (int r = 0; r < 4; ++r) {
            int gr = row0 + q * 4 + r;
            if (gr < n)
                Hout8[(size_t)gr * 128 + nt * 16 + m] = f2e5(acc[nt][r] * dv[r]);
        }
    }
}

// ---------- GEMM layer-1 variant: fp32 A input, bf16 MFMA ----------
__global__ __launch_bounds__(256, 4) void gemm_scale_f32(const float* __restrict__ Xf,
                                                         const ushort_t* __restrict__ Wt,
                                                         const float* __restrict__ dinv,
                                                         u8_t* __restrict__ Hout8, int n) {
    __shared__ ushort_t lds[128 * 136];
    int tid = threadIdx.x;
    for (int i = tid; i < 128 * 16; i += 256) {
        int r = i >> 4, c8 = (i & 15) << 3;
        *(uint32x4*)(lds + r * 136 + c8) = *(const uint32x4*)(Wt + r * 128 + c8);
    }
    __syncthreads();
    int lane = tid & 63, wave = tid >> 6;
    int m = lane & 15, q = lane >> 4;
    int row0 = blockIdx.x * 64 + wave * 16;
    int ar = row0 + m;
    if (ar > n - 1) ar = n - 1;
    bf16x8 a[4];
#pragma unroll
    for (int ks = 0; ks < 4; ++ks) {
        const float* p = Xf + (size_t)ar * 128 + ks * 32 + q * 8;
        f32x4 lo = *(const f32x4*)p;
        f32x4 hi = *(const f32x4*)(p + 4);
        ushort_t t[8];
        t[0] = f2b(lo[0]); t[1] = f2b(lo[1]); t[2] = f2b(lo[2]); t[3] = f2b(lo[3]);
        t[4] = f2b(hi[0]); t[5] = f2b(hi[1]); t[6] = f2b(hi[2]); t[7] = f2b(hi[3]);
        a[ks] = __builtin_bit_cast(bf16x8, *(uint32x4*)t);
    }
    f32x4 acc[8];
    f32x4 zero = {0.f, 0.f, 0.f, 0.f};
#pragma unroll
    for (int nt = 0; nt < 8; ++nt) acc[nt] = zero;
#pragma unroll
    for (int nt = 0; nt < 8; ++nt) {
#pragma unroll
        for (int ks = 0; ks < 4; ++ks) {
            bf16x8 b = __builtin_bit_cast(bf16x8,
                *(const uint32x4*)(lds + (nt * 16 + m) * 136 + ks * 32 + q * 8));
            acc[nt] = __builtin_amdgcn_mfma_f32_16x16x32_bf16(a[ks], b, acc[nt], 0, 0, 0);
        }
    }
    float dv[4];
#pragma unroll
    for (int r = 0; r < 4; ++r) {
        int gr = row0 + q * 4 + r;
        dv[r] = (gr < n) ? dinv[gr] : 0.f;
    }
#pragma unroll
    for (int nt = 0; nt < 8; ++nt) {
#pragma unroll
        for (int r = 0; r < 4; ++r) {
            int gr = row0 + q * 4 + r;
            if (gr < n)
                Hout8[(size_t)gr * 128 + nt * 16 + m] = f2e5(acc[nt][r] * dv[r]);
        }
    }
}

// gather+accumulate over the PADDED CSR (R6's proven memory pattern, unchanged).
__device__ __forceinline__ void agg_core(const u8_t* __restrict__ Hs8,
                                         const int* __restrict__ adj,
                                         int beg, int pd, int g, uint_t colb,
                                         h2* acc) {
    int e = 0;
    for (; e + 16 <= pd; e += 16) {
        const int4 sv = *(const int4*)(adj + beg + e + g * 4);
        uint_t o0 = ((uint_t)sv.x << 7) | colb;
        uint_t o1 = ((uint_t)sv.y << 7) | colb;
        uint_t o2 = ((uint_t)sv.z << 7) | colb;
        uint_t o3 = ((uint_t)sv.w << 7) | colb;
        uint32x2 w0 = *(const uint32x2*)(Hs8 + o0);
        uint32x2 w1 = *(const uint32x2*)(Hs8 + o1);
        uint32x2 w2 = *(const uint32x2*)(Hs8 + o2);
        uint32x2 w3 = *(const uint32x2*)(Hs8 + o3);
        upk_add(w0[0], acc); upk_add(w0[1], acc + 2);
        upk_add(w1[0], acc); upk_add(w1[1], acc + 2);
        upk_add(w2[0], acc); upk_add(w2[1], acc + 2);
        upk_add(w3[0], acc); upk_add(w3[1], acc + 2);
    }
    if (e < pd) {   // 8-edge tail (pd is a multiple of 8; condition is wave-uniform)
        const int2 sv = *(const int2*)(adj + beg + e + g * 2);
        uint_t o0 = ((uint_t)sv.x << 7) | colb;
        uint_t o1 = ((uint_t)sv.y << 7) | colb;
        uint32x2 w0 = *(const uint32x2*)(Hs8 + o0);
        uint32x2 w1 = *(const uint32x2*)(Hs8 + o1);
        upk_add(w0[0], acc); upk_add(w0[1], acc + 2);
        upk_add(w1[0], acc); upk_add(w1[1], acc + 2);
    }
}

// slot-reduce: sum acc over the 4 edge slots (lane bits 4..5); l16 bits untouched
__device__ __forceinline__ void slot_reduce(h2* acc) {
#pragma unroll
    for (int k = 0; k < 4; ++k) {
        uint_t v = __builtin_bit_cast(uint_t, acc[k]);
        acc[k] += __builtin_bit_cast(h2, (uint_t)__shfl_xor(v, 16, 64));
        v = __builtin_bit_cast(uint_t, acc[k]);
        acc[k] += __builtin_bit_cast(h2, (uint_t)__shfl_xor(v, 32, 64));
    }
}

// ---------- aggregation (layer 1): Out8 = e5m2(relu(dinv*(sum Hs8) + b)) ----------
// R13: output e5m2 directly (12.8MB) instead of bf16 (25.6MB) — layer-2 GEMM
// consumes fp8 via exact f16 expansion, so the only cost is one quantization
// that previously happened after the GEMM anyway.
__global__ __launch_bounds__(256, 4) void agg_kernel(const u8_t* __restrict__ Hs8,
                                                     const int* __restrict__ adj,
                                                     const int* __restrict__ offs,
                                                     const int* __restrict__ dgr,
                                                     const float* __restrict__ dinv,
                                                     const float* __restrict__ bias,
                                                     u8_t* __restrict__ Out8, int n) {
    int node = blockIdx.x * 4 + (threadIdx.x >> 6);
    if (node >= n) return;
    int lane = threadIdx.x & 63;
    int g = lane >> 4;           // edge slot 0..3
    int l16 = lane & 15;         // column group: 8 cols each
    uint_t colb = (uint_t)l16 * 8;
    const int beg = offs[node];
    const int pd  = dgr[node];
    h2 acc[4];
    h2 hz = {(_Float16)0.f, (_Float16)0.f};
#pragma unroll
    for (int k = 0; k < 4; ++k) acc[k] = hz;
    agg_core(Hs8, adj, beg, pd, g, colb, acc);
    slot_reduce(acc);
    if (g == 0) {
        float di = dinv[node];
        u8_t o[8];
#pragma unroll
        for (int k = 0; k < 4; ++k) {
            float f0 = (float)acc[k][0];
            float f1 = (float)acc[k][1];
            o[2 * k]     = f2e5(fmaxf(di * f0 + bias[colb + 2 * k], 0.f));
            o[2 * k + 1] = f2e5(fmaxf(di * f1 + bias[colb + 2 * k + 1], 0.f));
        }
        *(uint32x2*)(Out8 + (size_t)node * 128 + colb) = *(uint32x2*)o;
    }
}

// ---------- aggregation (layer 2) + classifier dot + fused pool accumulate ----------
// S[node] = relu(...) . Wc, atomically accumulated into gsum[batch[node]].
// 100K adds over ~512 counters; fp32 reorder noise well under the e5m2 error budget.
__global__ __launch_bounds__(256, 4) void agg_pool_kernel(const u8_t* __restrict__ Hs8,
                                                          const int* __restrict__ adj,
                                                          const int* __restrict__ offs,
                                                          const int* __restrict__ dgr,
                                                          const float* __restrict__ dinv,
                                                          const float* __restrict__ bias,
                                                          const float* __restrict__ Wc,
                                                          const int* __restrict__ batch,
                                                          float* __restrict__ gsum, int n) {
    int node = blockIdx.x * 4 + (threadIdx.x >> 6);
    if (node >= n) return;
    int lane = threadIdx.x & 63;
    int g = lane >> 4;
    int l16 = lane & 15;
    uint_t colb = (uint_t)l16 * 8;
    const int beg = offs[node];
    const int pd  = dgr[node];
    h2 acc[4];
    h2 hz = {(_Float16)0.f, (_Float16)0.f};
#pragma unroll
    for (int k = 0; k < 4; ++k) acc[k] = hz;
    agg_core(Hs8, adj, beg, pd, g, colb, acc);
    slot_reduce(acc);
    // classifier dot in-register: g==0 lanes hold 8 full cols each
    float local = 0.f;
    float di = dinv[node];
#pragma unroll
    for (int k = 0; k < 4; ++k) {
        float f0 = fmaxf(di * (float)acc[k][0] + bias[colb + 2 * k], 0.f);
        float f1 = fmaxf(di * (float)acc[k][1] + bias[colb + 2 * k + 1], 0.f);
        local += f0 * Wc[colb + 2 * k] + f1 * Wc[colb + 2 * k + 1];
    }
    // reduce across l16 (lane bits 0..3); g bits untouched so g==0 lanes stay pure
    local += __shfl_xor(local, 1, 64);
    local += __shfl_xor(local, 2, 64);
    local += __shfl_xor(local, 4, 64);
    local += __shfl_xor(local, 8, 64);
    if (lane == 0) atomicAdd(&gsum[batch[node]], local);
}

// ---------- pool finish: out[g] = sigmoid(gsum[g]/count[g] + bc) ----------
__global__ __launch_bounds__(512) void pool_fin(const float* __restrict__ gsum,
                                                const int* __restrict__ batch,
                                                const float* __restrict__ bc,
                                                float* __restrict__ out, int n, int G) {
    int g = blockIdx.x * 512 + threadIdx.x;
    if (g >= G) return;
    int lo = 0, hi = n;
    while (lo < hi) { int mid = (lo + hi) >> 1; if (batch[mid] < g) lo = mid + 1; else hi = mid; }
    int start = lo;
    hi = n;
    while (lo < hi) { int mid = (lo + hi) >> 1; if (batch[mid] < g + 1) lo = mid + 1; else hi = mid; }
    int cnt = lo - start;
    float z = gsum[g] / (float)(cnt > 0 ? cnt : 1) + bc[0];
    out[g] = 1.f / (1.f + expf(-z));
}

extern "C" void kernel_launch(void* const* d_in, const int* in_sizes, int n_in,
                              void* d_out, int out_size, void* d_ws, size_t ws_size,
                              hipStream_t stream) {
    const float* X     = (const float*)d_in[0];
    const int* ei      = (const int*)d_in[1];
    const int* batch   = (const int*)d_in[2];
    const float* W1    = (const float*)d_in[3];
    const float* b1    = (const float*)d_in[4];
    const float* W2    = (const float*)d_in[5];
    const float* b2    = (const float*)d_in[6];
    const float* Wc    = (const float*)d_in[7];
    const float* bc    = (const float*)d_in[8];

    const int N = in_sizes[2];
    const int E = in_sizes[1] / 2;
    const int G = out_size;
    const int* srcv = ei;
    const int* dstv = ei + E;

    const int NBLK = (E + EPB - 1) / EPB;      // edge chunks (~625)
    const int B    = (N + MSK) >> NSH;         // dst buckets (~196)
    const int n0   = B * NBLK;                 // histogram matrix (~122.5K)
    const int g1   = (n0 + 255) / 256;         // <= 512 by construction (~479)

    char* p = (char*)d_ws;
    auto alloc = [&](size_t bytes) -> void* {
        void* r = (void*)p;
        p += (bytes + 255) & ~(size_t)255;
        return r;
    };
    int* H         = (int*)alloc((size_t)n0 * 4);
    int* Hex       = (int*)alloc((size_t)n0 * 4);
    int* S1        = (int*)alloc((size_t)g1 * 4);
    int* S1ex      = (int*)alloc((size_t)g1 * 4);
    uint_t* packed = (uint_t*)alloc((size_t)E * 4);
    int* adj       = (int*)alloc(((size_t)E + (size_t)B * BPAD + 4224) * 4); // padded CSR
    int* offs      = (int*)alloc(((size_t)N + 1) * 4);
    int* dgr       = (int*)alloc((size_t)N * 4);
    float* dinv    = (float*)alloc((size_t)N * 4);
    ushort_t* W1t  = (ushort_t*)alloc(16384 * 2);
    ushort_t* W2t  = (ushort_t*)alloc(16384 * 2);
    u8_t* h8       = (u8_t*)alloc(((size_t)N + 1) * 128);   // gather table (+ zero row)
    u8_t* h8b      = (u8_t*)alloc((size_t)N * 128);         // layer-1 out / layer-2 GEMM in
    float* gsum    = (float*)alloc((size_t)(G > 512 ? G : 512) * 4);

    // ---- CSR build (LDS atomics only; 6 dispatches, 2-level scan) ----
    p1_hist<<<NBLK + 129, 256, 0, stream>>>(dstv, H, W1, W2, W1t, W2t, h8, gsum,
                                            E, NBLK, B, N, G);
    reduce256<<<g1, 256, 0, stream>>>(H, S1, n0);
    scan_small<<<1, 512, 0, stream>>>(S1, S1ex, g1);
    scan256ex<<<g1, 256, 0, stream>>>(H, S1ex, Hex, n0);
    p3_scatter<<<NBLK, 256, 0, stream>>>(srcv, dstv, Hex, packed, E, NBLK, B);
    p4_build<<<B, 512, 0, stream>>>(packed, Hex, adj, offs, dgr, dinv, E, N, NBLK, B);

    const int GB = (N + 63) / 64;
    const int AB = (N + 3) / 4;
    // layer 1 (cast fused into GEMM; fp8 e5m2 gather table)
    gemm_scale_f32<<<GB, 256, 0, stream>>>(X, W1t, dinv, h8, N);
    agg_kernel<<<AB, 256, 0, stream>>>(h8, adj, offs, dgr, dinv, b1, h8b, N);
    // layer 2 (fp8 A-input f16-MFMA GEMM; classifier dot + pool accumulate fused)
    gemm_scale<<<GB, 256, 0, stream>>>(h8b, W2t, dinv, h8, N);
    agg_pool_kernel<<<AB, 256, 0, stream>>>(h8, adj, offs, dgr, dinv, b2, Wc,
                                            batch, gsum, N);
    // pool finish: mean + sigmoid per graph
    pool_fin<<<(G + 511) / 512, 512, 0, stream>>>(gsum, batch, bc, (float*)d_out, N, G);
}

// Round 14
// 339.857 us; speedup vs baseline: 1.6863x; 1.6863x over previous
//
#include <hip/hip_runtime.h>

typedef unsigned short ushort_t;
typedef unsigned int uint_t;
typedef unsigned char u8_t;

typedef __bf16 bf16x8 __attribute__((ext_vector_type(8)));
typedef _Float16 f16x8 __attribute__((ext_vector_type(8)));
typedef float f32x4 __attribute__((ext_vector_type(4)));
typedef uint_t uint32x4 __attribute__((ext_vector_type(4)));
typedef uint_t uint32x2 __attribute__((ext_vector_type(2)));
typedef _Float16 h2 __attribute__((ext_vector_type(2)));

#define EPB 5120     // edges per build chunk (NBLK=625 -> 2.4 blocks/CU in p1/p3)
#define NSH 9        // bucket = dst >> NSH (512 nodes/bucket, B=196)
                     // R11 lesson: NSH=7 gave 26B scatter runs -> 5.7x write amp.
#define MSK 511      // (1<<NSH)-1
#define BPAD 4104    // per-bucket adj pad slack: 8*512 worst case + 8 align (mult of 8)

// R13 lesson (atomics, pole 2): fusing pool as atomicAdd(&gsum[batch[node]]) took
// agg_pool 60->285us. batch is SORTED, so all resident blocks hit the same 1-2 lines
// with device-scope RMW across 8 non-coherent XCDs -> same-line serialization.
// (R9 was the other pole: scattered 4B atomics -> 15x partial-line write amp.)
// Pool therefore stays a deterministic per-node store + tiny separate kernel.

// ---------- bf16 helpers (RNE fp32->bf16; bit-shift bf16->fp32) ----------
__device__ __forceinline__ float b2f(ushort_t u) {
    union { uint_t ui; float f; } c; c.ui = ((uint_t)u) << 16; return c.f;
}
__device__ __forceinline__ ushort_t f2b(float f) {
    union { float f; uint_t ui; } c; c.f = f;
    uint_t u = c.ui;
    uint_t r = (u + 0x7fffu + ((u >> 16) & 1u)) >> 16;
    return (ushort_t)r;
}
// fp32 -> fp8 e5m2 (RNE via f16; e5m2 = top byte of f16)
__device__ __forceinline__ u8_t f2e5(float x) {
    ushort_t h = __builtin_bit_cast(ushort_t, (_Float16)x);
    uint_t r = ((uint_t)h + 0x7Fu + ((h >> 8) & 1u)) >> 8;
    return (u8_t)r;
}
// unpack dword of 4 e5m2 bytes into 2 packed-f16 pairs and accumulate
// (e5m2<<8 is an EXACT f16: same exponent bias/width, mantissa zero-extended)
__device__ __forceinline__ void upk_add(uint_t d, h2* acc) {
    uint_t A = __builtin_amdgcn_perm(0u, d, 0x010C000Cu);  // (b0<<8, b1<<8) = two f16
    uint_t B = __builtin_amdgcn_perm(0u, d, 0x030C020Cu);  // (b2<<8, b3<<8)
    acc[0] += __builtin_bit_cast(h2, A);
    acc[1] += __builtin_bit_cast(h2, B);
}

// ---------- P1: per-chunk bucket histogram (LDS atomics only) + weight transpose ----------
// extra blocks: [NBLK, NBLK+128) transpose W1 (bf16) / W2 (f16);
// block NBLK+128 zeroes h8 row N.
__global__ __launch_bounds__(256) void p1_hist(const int* __restrict__ dst,
                                               int* __restrict__ H,
                                               const float* __restrict__ W1,
                                               const float* __restrict__ W2,
                                               ushort_t* __restrict__ W1t,
                                               ushort_t* __restrict__ W2t,
                                               u8_t* __restrict__ h8z,
                                               int E, int NBLK, int B, int N) {
    int t = threadIdx.x, c = blockIdx.x;
    if (c >= NBLK + 128) {                 // zero h8 pad row
        if (t < 32) ((uint_t*)h8z)[(size_t)N * 32 + t] = 0u;
        return;
    }
    if (c >= NBLK) {
        int idx = (c - NBLK) * 256 + t;   // 0..32767
        int sel = idx >> 14;
        int i = idx & 16383;
        int k = i >> 7, nn = i & 127;
        if (sel) {  // W2 -> f16 bits (layer-2 GEMM uses f16 MFMA vs fp8 A-operand)
            W2t[nn * 128 + k] = __builtin_bit_cast(ushort_t, (_Float16)W2[k * 128 + nn]);
        } else {    // W1 -> bf16 bits
            W1t[nn * 128 + k] = f2b(W1[k * 128 + nn]);
        }
        return;
    }
    __shared__ int hist[256];
    if (t < 256) hist[t] = 0;
    __syncthreads();
    int base = c * EPB;
    int lim = min(E - base, EPB);
    for (int i = t; i < lim; i += 256)
        atomicAdd(&hist[dst[base + i] >> NSH], 1);
    __syncthreads();
    if (t < B) H[t * NBLK + c] = hist[t];
}

// ---------- scan: per-256-chunk sums ----------
__global__ __launch_bounds__(256) void reduce256(const int* __restrict__ in,
                                                 int* __restrict__ bsums, int n) {
    __shared__ int s[256];
    int t = threadIdx.x, g = blockIdx.x * 256 + t;
    s[t] = (g < n) ? in[g] : 0;
    __syncthreads();
    for (int o = 128; o > 0; o >>= 1) {
        if (t < o) s[t] += s[t + o];
        __syncthreads();
    }
    if (t == 0) bsums[blockIdx.x] = s[0];
}

// ---------- scan: single-block exclusive scan (n <= 512) ----------
__global__ __launch_bounds__(512) void scan_small(const int* __restrict__ in,
                                                  int* __restrict__ outEx, int n) {
    __shared__ int s[512];
    int t = threadIdx.x;
    int v = (t < n) ? in[t] : 0;
    s[t] = v;
    __syncthreads();
    for (int o = 1; o < 512; o <<= 1) {
        int x = 0;
        if (t >= o) x = s[t - o];
        __syncthreads();
        s[t] += x;
        __syncthreads();
    }
    if (t < n) outEx[t] = s[t] - v;
}

// ---------- scan: per-chunk exclusive scan + chunk offset ----------
__global__ __launch_bounds__(256) void scan256ex(const int* __restrict__ in,
                                                 const int* __restrict__ boffs,
                                                 int* __restrict__ outEx, int n) {
    __shared__ int s[256];
    int t = threadIdx.x, g = blockIdx.x * 256 + t;
    int v = (g < n) ? in[g] : 0;
    s[t] = v;
    __syncthreads();
    for (int o = 1; o < 256; o <<= 1) {
        int x = 0;
        if (t >= o) x = s[t - o];
        __syncthreads();
        s[t] += x;
        __syncthreads();
    }
    if (g < n) outEx[g] = boffs[blockIdx.x] + s[t] - v;
}

// ---------- P3: partition scatter by dst-bucket (LDS rank) ----------
__global__ __launch_bounds__(256) void p3_scatter(const int* __restrict__ src,
                                                  const int* __restrict__ dst,
                                                  const int* __restrict__ Hex,
                                                  uint_t* __restrict__ packed,
                                                  int E, int NBLK, int B) {
    __shared__ int offsL[256];
    __shared__ int cur[256];
    int t = threadIdx.x, c = blockIdx.x;
    if (t < B) {
        offsL[t] = Hex[t * NBLK + c];
        cur[t] = 0;
    }
    __syncthreads();
    int base = c * EPB;
    int lim = min(E - base, EPB);
    for (int i = t; i < lim; i += 256) {
        int d = dst[base + i];
        int s = src[base + i];
        int b = d >> NSH;
        int r = atomicAdd(&cur[b], 1);
        packed[offsL[b] + r] = ((uint_t)s << NSH) | (uint_t)(d & MSK);
    }
}

// ---------- P4: per-bucket padded CSR build (512 nodes/bucket, streamed twice) ------
__global__ __launch_bounds__(512) void p4_build(const uint_t* __restrict__ packed,
                                                const int* __restrict__ Hex,
                                                int* __restrict__ adj,
                                                int* __restrict__ offs,
                                                int* __restrict__ dgr,
                                                float* __restrict__ dinv,
                                                int E, int N, int NBLK, int B) {
    __shared__ int dcnt[512], loc[512], cur[512], sps[512];
    int t = threadIdx.x, b = blockIdx.x;
    int bs = Hex[b * NBLK];
    int be = (b + 1 < B) ? Hex[(b + 1) * NBLK] : E;
    int m = be - bs;
    dcnt[t] = 0;
    __syncthreads();
    for (int i = t; i < m; i += 512)
        atomicAdd(&dcnt[packed[bs + i] & MSK], 1);
    __syncthreads();
    int d = dcnt[t];
    int pd = (d + 8) & ~7;   // (deg + 1 self) rounded up to 8
    sps[t] = pd;
    __syncthreads();
    for (int o = 1; o < 512; o <<= 1) {   // inclusive scan over 512 padded degrees
        int x = 0;
        if (t >= o) x = sps[t - o];
        __syncthreads();
        sps[t] += x;
        __syncthreads();
    }
    int bsp = ((bs + 7) & ~7) + b * BPAD;   // aligned padded bucket base
    int ex = sps[t] - pd;
    int node = b * 512 + t;
    if (node < N) {
        int nbase = bsp + ex;
        offs[node] = nbase;
        dgr[node]  = pd;
        dinv[node] = rsqrtf((float)(d + 1));
        adj[nbase] = node;                        // self-loop first
        for (int i = d + 1; i < pd; ++i)
            adj[nbase + i] = N;                   // zero-row pads
    }
    loc[t] = ex + 1;   // neighbors start after the self entry
    cur[t] = 0;
    __syncthreads();
    for (int i = t; i < m; i += 512) {
        uint_t p = packed[bs + i];
        int l = p & MSK;
        int r = atomicAdd(&cur[l], 1);
        adj[bsp + loc[l] + r] = (int)(p >> NSH);
    }
}

// ---------- GEMM layer-2 (fp8 e5m2 A in, f16 MFMA): H8 = e5m2((A@W2)*dinv) ----------
// A bytes <<8 are exact f16; B = W2t stored as f16 (MORE precise than the old bf16).
__global__ __launch_bounds__(256, 4) void gemm_scale(const u8_t* __restrict__ Xin8,
                                                     const ushort_t* __restrict__ Wt,
                                                     const float* __restrict__ dinv,
                                                     u8_t* __restrict__ Hout8, int n) {
    __shared__ ushort_t lds[128 * 136];
    int tid = threadIdx.x;
    for (int i = tid; i < 128 * 16; i += 256) {
        int r = i >> 4, c8 = (i & 15) << 3;
        *(uint32x4*)(lds + r * 136 + c8) = *(const uint32x4*)(Wt + r * 128 + c8);
    }
    __syncthreads();
    int lane = tid & 63, wave = tid >> 6;
    int m = lane & 15, q = lane >> 4;
    int row0 = blockIdx.x * 64 + wave * 16;
    int ar = row0 + m;
    if (ar > n - 1) ar = n - 1;
    f16x8 a[4];
#pragma unroll
    for (int ks = 0; ks < 4; ++ks) {
        uint32x2 dv8 = *(const uint32x2*)(Xin8 + (size_t)ar * 128 + ks * 32 + q * 8);
        uint_t tw[4];
        tw[0] = __builtin_amdgcn_perm(0u, dv8[0], 0x010C000Cu);  // (b0,b1) as f16
        tw[1] = __builtin_amdgcn_perm(0u, dv8[0], 0x030C020Cu);  // (b2,b3)
        tw[2] = __builtin_amdgcn_perm(0u, dv8[1], 0x010C000Cu);  // (b4,b5)
        tw[3] = __builtin_amdgcn_perm(0u, dv8[1], 0x030C020Cu);  // (b6,b7)
        a[ks] = __builtin_bit_cast(f16x8, *(uint32x4*)tw);
    }
    f32x4 acc[8];
    f32x4 zero = {0.f, 0.f, 0.f, 0.f};
#pragma unroll
    for (int nt = 0; nt < 8; ++nt) acc[nt] = zero;
#pragma unroll
    for (int nt = 0; nt < 8; ++nt) {
#pragma unroll
        for (int ks = 0; ks < 4; ++ks) {
            f16x8 b = __builtin_bit_cast(f16x8,
                *(const uint32x4*)(lds + (nt * 16 + m) * 136 + ks * 32 + q * 8));
            acc[nt] = __builtin_amdgcn_mfma_f32_16x16x32_f16(a[ks], b, acc[nt], 0, 0, 0);
        }
    }
    float dv[4];
#pragma unroll
    for (int r = 0; r < 4; ++r) {
        int gr = row0 + q * 4 + r;
        dv[r] = (gr < n) ? dinv[gr] : 0.f;
    }
#pragma unroll
    for (int nt = 0; nt < 8; ++nt) {
#pragma unroll
        for (int r = 0; r < 4; ++r) {
            int gr = row0 + q * 4 + r;
            if (gr < n)
                Hout8[(size_t)gr * 128 + nt * 16 + m] = f2e5(acc[nt][r] * dv[r]);
        }
    }
}

// ---------- GEMM layer-1 variant: fp32 A input, bf16 MFMA ----------
__global__ __launch_bounds__(256, 4) void gemm_scale_f32(const float* __restrict__ Xf,
                                                         const ushort_t* __restrict__ Wt,
                                                         const float* __restrict__ dinv,
                                                         u8_t* __restrict__ Hout8, int n) {
    __shared__ ushort_t lds[128 * 136];
    int tid = threadIdx.x;
    for (int i = tid; i < 128 * 16; i += 256) {
        int r = i >> 4, c8 = (i & 15) << 3;
        *(uint32x4*)(lds + r * 136 + c8) = *(const uint32x4*)(Wt + r * 128 + c8);
    }
    __syncthreads();
    int lane = tid & 63, wave = tid >> 6;
    int m = lane & 15, q = lane >> 4;
    int row0 = blockIdx.x * 64 + wave * 16;
    int ar = row0 + m;
    if (ar > n - 1) ar = n - 1;
    bf16x8 a[4];
#pragma unroll
    for (int ks = 0; ks < 4; ++ks) {
        const float* p = Xf + (size_t)ar * 128 + ks * 32 + q * 8;
        f32x4 lo = *(const f32x4*)p;
        f32x4 hi = *(const f32x4*)(p + 4);
        ushort_t t[8];
        t[0] = f2b(lo[0]); t[1] = f2b(lo[1]); t[2] = f2b(lo[2]); t[3] = f2b(lo[3]);
        t[4] = f2b(hi[0]); t[5] = f2b(hi[1]); t[6] = f2b(hi[2]); t[7] = f2b(hi[3]);
        a[ks] = __builtin_bit_cast(bf16x8, *(uint32x4*)t);
    }
    f32x4 acc[8];
    f32x4 zero = {0.f, 0.f, 0.f, 0.f};
#pragma unroll
    for (int nt = 0; nt < 8; ++nt) acc[nt] = zero;
#pragma unroll
    for (int nt = 0; nt < 8; ++nt) {
#pragma unroll
        for (int ks = 0; ks < 4; ++ks) {
            bf16x8 b = __builtin_bit_cast(bf16x8,
                *(const uint32x4*)(lds + (nt * 16 + m) * 136 + ks * 32 + q * 8));
            acc[nt] = __builtin_amdgcn_mfma_f32_16x16x32_bf16(a[ks], b, acc[nt], 0, 0, 0);
        }
    }
    float dv[4];
#pragma unroll
    for (int r = 0; r < 4; ++r) {
        int gr = row0 + q * 4 + r;
        dv[r] = (gr < n) ? dinv[gr] : 0.f;
    }
#pragma unroll
    for (int nt = 0; nt < 8; ++nt) {
#pragma unroll
        for (int r = 0; r < 4; ++r) {
            int gr = row0 + q * 4 + r;
            if (gr < n)
                Hout8[(size_t)gr * 128 + nt * 16 + m] = f2e5(acc[nt][r] * dv[r]);
        }
    }
}

// gather+accumulate over the PADDED CSR (R6's proven memory pattern, unchanged).
__device__ __forceinline__ void agg_core(const u8_t* __restrict__ Hs8,
                                         const int* __restrict__ adj,
                                         int beg, int pd, int g, uint_t colb,
                                         h2* acc) {
    int e = 0;
    for (; e + 16 <= pd; e += 16) {
        const int4 sv = *(const int4*)(adj + beg + e + g * 4);
        uint_t o0 = ((uint_t)sv.x << 7) | colb;
        uint_t o1 = ((uint_t)sv.y << 7) | colb;
        uint_t o2 = ((uint_t)sv.z << 7) | colb;
        uint_t o3 = ((uint_t)sv.w << 7) | colb;
        uint32x2 w0 = *(const uint32x2*)(Hs8 + o0);
        uint32x2 w1 = *(const uint32x2*)(Hs8 + o1);
        uint32x2 w2 = *(const uint32x2*)(Hs8 + o2);
        uint32x2 w3 = *(const uint32x2*)(Hs8 + o3);
        upk_add(w0[0], acc); upk_add(w0[1], acc + 2);
        upk_add(w1[0], acc); upk_add(w1[1], acc + 2);
        upk_add(w2[0], acc); upk_add(w2[1], acc + 2);
        upk_add(w3[0], acc); upk_add(w3[1], acc + 2);
    }
    if (e < pd) {   // 8-edge tail (pd is a multiple of 8; condition is wave-uniform)
        const int2 sv = *(const int2*)(adj + beg + e + g * 2);
        uint_t o0 = ((uint_t)sv.x << 7) | colb;
        uint_t o1 = ((uint_t)sv.y << 7) | colb;
        uint32x2 w0 = *(const uint32x2*)(Hs8 + o0);
        uint32x2 w1 = *(const uint32x2*)(Hs8 + o1);
        upk_add(w0[0], acc); upk_add(w0[1], acc + 2);
        upk_add(w1[0], acc); upk_add(w1[1], acc + 2);
    }
}

// slot-reduce: sum acc over the 4 edge slots (lane bits 4..5); l16 bits untouched
__device__ __forceinline__ void slot_reduce(h2* acc) {
#pragma unroll
    for (int k = 0; k < 4; ++k) {
        uint_t v = __builtin_bit_cast(uint_t, acc[k]);
        acc[k] += __builtin_bit_cast(h2, (uint_t)__shfl_xor(v, 16, 64));
        v = __builtin_bit_cast(uint_t, acc[k]);
        acc[k] += __builtin_bit_cast(h2, (uint_t)__shfl_xor(v, 32, 64));
    }
}

// ---------- aggregation (layer 1): Out8 = e5m2(relu(dinv*(sum Hs8) + b)) ----------
// fp8 output (12.8MB vs bf16's 25.6MB); layer-2 GEMM consumes fp8 via exact f16
// expansion, so the only cost is a quantization that happened post-GEMM anyway.
__global__ __launch_bounds__(256, 4) void agg_kernel(const u8_t* __restrict__ Hs8,
                                                     const int* __restrict__ adj,
                                                     const int* __restrict__ offs,
                                                     const int* __restrict__ dgr,
                                                     const float* __restrict__ dinv,
                                                     const float* __restrict__ bias,
                                                     u8_t* __restrict__ Out8, int n) {
    int node = blockIdx.x * 4 + (threadIdx.x >> 6);
    if (node >= n) return;
    int lane = threadIdx.x & 63;
    int g = lane >> 4;           // edge slot 0..3
    int l16 = lane & 15;         // column group: 8 cols each
    uint_t colb = (uint_t)l16 * 8;
    const int beg = offs[node];
    const int pd  = dgr[node];
    h2 acc[4];
    h2 hz = {(_Float16)0.f, (_Float16)0.f};
#pragma unroll
    for (int k = 0; k < 4; ++k) acc[k] = hz;
    agg_core(Hs8, adj, beg, pd, g, colb, acc);
    slot_reduce(acc);
    if (g == 0) {
        float di = dinv[node];
        u8_t o[8];
#pragma unroll
        for (int k = 0; k < 4; ++k) {
            float f0 = (float)acc[k][0];
            float f1 = (float)acc[k][1];
            o[2 * k]     = f2e5(fmaxf(di * f0 + bias[colb + 2 * k], 0.f));
            o[2 * k + 1] = f2e5(fmaxf(di * f1 + bias[colb + 2 * k + 1], 0.f));
        }
        *(uint32x2*)(Out8 + (size_t)node * 128 + colb) = *(uint32x2*)o;
    }
}

// ---------- aggregation (layer 2) + classifier dot: S[i] = relu(...) . Wc ----------
// Deterministic per-node store (R13 lesson: NO atomic pool accumulate).
__global__ __launch_bounds__(256, 4) void agg_pool_kernel(const u8_t* __restrict__ Hs8,
                                                          const int* __restrict__ adj,
                                                          const int* __restrict__ offs,
                                                          const int* __restrict__ dgr,
                                                          const float* __restrict__ dinv,
                                                          const float* __restrict__ bias,
                                                          const float* __restrict__ Wc,
                                                          float* __restrict__ Sout, int n) {
    int node = blockIdx.x * 4 + (threadIdx.x >> 6);
    if (node >= n) return;
    int lane = threadIdx.x & 63;
    int g = lane >> 4;
    int l16 = lane & 15;
    uint_t colb = (uint_t)l16 * 8;
    const int beg = offs[node];
    const int pd  = dgr[node];
    h2 acc[4];
    h2 hz = {(_Float16)0.f, (_Float16)0.f};
#pragma unroll
    for (int k = 0; k < 4; ++k) acc[k] = hz;
    agg_core(Hs8, adj, beg, pd, g, colb, acc);
    slot_reduce(acc);
    // classifier dot in-register: g==0 lanes hold 8 full cols each
    float local = 0.f;
    float di = dinv[node];
#pragma unroll
    for (int k = 0; k < 4; ++k) {
        float f0 = fmaxf(di * (float)acc[k][0] + bias[colb + 2 * k], 0.f);
        float f1 = fmaxf(di * (float)acc[k][1] + bias[colb + 2 * k + 1], 0.f);
        local += f0 * Wc[colb + 2 * k] + f1 * Wc[colb + 2 * k + 1];
    }
    // reduce across l16 (lane bits 0..3); g bits untouched so g==0 lanes stay pure
    local += __shfl_xor(local, 1, 64);
    local += __shfl_xor(local, 2, 64);
    local += __shfl_xor(local, 4, 64);
    local += __shfl_xor(local, 8, 64);
    if (lane == 0) Sout[node] = local;
}

// ---------- pooling: out[g] = sigmoid(mean_{i in g} S[i] + bc) ----------
__global__ __launch_bounds__(256) void pool2_kernel(const float* __restrict__ S,
                                                    const int* __restrict__ batch,
                                                    const float* __restrict__ bc,
                                                    float* __restrict__ out, int n) {
    int g = blockIdx.x;
    int t = threadIdx.x;
    int lo = 0, hi = n;
    while (lo < hi) { int mid = (lo + hi) >> 1; if (batch[mid] < g) lo = mid + 1; else hi = mid; }
    int start = lo;
    hi = n;
    while (lo < hi) { int mid = (lo + hi) >> 1; if (batch[mid] < g + 1) lo = mid + 1; else hi = mid; }
    int stop = lo;
    float s = 0.f;
    for (int i = start + t; i < stop; i += 256) s += S[i];
    __shared__ float red[256];
    red[t] = s;
    __syncthreads();
    for (int o = 128; o > 0; o >>= 1) {
        if (t < o) red[t] += red[t + o];
        __syncthreads();
    }
    if (t == 0) {
        int cg = stop - start;
        float z = red[0] / (float)(cg > 0 ? cg : 1) + bc[0];
        out[g] = 1.f / (1.f + expf(-z));
    }
}

extern "C" void kernel_launch(void* const* d_in, const int* in_sizes, int n_in,
                              void* d_out, int out_size, void* d_ws, size_t ws_size,
                              hipStream_t stream) {
    const float* X     = (const float*)d_in[0];
    const int* ei      = (const int*)d_in[1];
    const int* batch   = (const int*)d_in[2];
    const float* W1    = (const float*)d_in[3];
    const float* b1    = (const float*)d_in[4];
    const float* W2    = (const float*)d_in[5];
    const float* b2    = (const float*)d_in[6];
    const float* Wc    = (const float*)d_in[7];
    const float* bc    = (const float*)d_in[8];

    const int N = in_sizes[2];
    const int E = in_sizes[1] / 2;
    const int G = out_size;
    const int* srcv = ei;
    const int* dstv = ei + E;

    const int NBLK = (E + EPB - 1) / EPB;      // edge chunks (~625)
    const int B    = (N + MSK) >> NSH;         // dst buckets (~196)
    const int n0   = B * NBLK;                 // histogram matrix (~122.5K)
    const int g1   = (n0 + 255) / 256;         // <= 512 by construction (~479)

    char* p = (char*)d_ws;
    auto alloc = [&](size_t bytes) -> void* {
        void* r = (void*)p;
        p += (bytes + 255) & ~(size_t)255;
        return r;
    };
    int* H         = (int*)alloc((size_t)n0 * 4);
    int* Hex       = (int*)alloc((size_t)n0 * 4);
    int* S1        = (int*)alloc((size_t)g1 * 4);
    int* S1ex      = (int*)alloc((size_t)g1 * 4);
    uint_t* packed = (uint_t*)alloc((size_t)E * 4);
    int* adj       = (int*)alloc(((size_t)E + (size_t)B * BPAD + 4224) * 4); // padded CSR
    int* offs      = (int*)alloc(((size_t)N + 1) * 4);
    int* dgr       = (int*)alloc((size_t)N * 4);
    float* dinv    = (float*)alloc((size_t)N * 4);
    ushort_t* W1t  = (ushort_t*)alloc(16384 * 2);
    ushort_t* W2t  = (ushort_t*)alloc(16384 * 2);
    u8_t* h8       = (u8_t*)alloc(((size_t)N + 1) * 128);   // gather table (+ zero row)
    u8_t* h8b      = (u8_t*)alloc((size_t)N * 128);         // layer-1 out / layer-2 GEMM in
    float* Snode   = (float*)alloc((size_t)N * 4);

    // ---- CSR build (LDS atomics only; 6 dispatches, 2-level scan) ----
    p1_hist<<<NBLK + 129, 256, 0, stream>>>(dstv, H, W1, W2, W1t, W2t, h8,
                                            E, NBLK, B, N);
    reduce256<<<g1, 256, 0, stream>>>(H, S1, n0);
    scan_small<<<1, 512, 0, stream>>>(S1, S1ex, g1);
    scan256ex<<<g1, 256, 0, stream>>>(H, S1ex, Hex, n0);
    p3_scatter<<<NBLK, 256, 0, stream>>>(srcv, dstv, Hex, packed, E, NBLK, B);
    p4_build<<<B, 512, 0, stream>>>(packed, Hex, adj, offs, dgr, dinv, E, N, NBLK, B);

    const int GB = (N + 63) / 64;
    const int AB = (N + 3) / 4;
    // layer 1 (cast fused into GEMM; fp8 e5m2 gather table)
    gemm_scale_f32<<<GB, 256, 0, stream>>>(X, W1t, dinv, h8, N);
    agg_kernel<<<AB, 256, 0, stream>>>(h8, adj, offs, dgr, dinv, b1, h8b, N);
    // layer 2 (fp8 A-input f16-MFMA GEMM; classifier dot fused into agg epilogue)
    gemm_scale<<<GB, 256, 0, stream>>>(h8b, W2t, dinv, h8, N);
    agg_pool_kernel<<<AB, 256, 0, stream>>>(h8, adj, offs, dgr, dinv, b2, Wc, Snode, N);
    // pool + sigmoid over per-node scalars
    pool2_kernel<<<G, 256, 0, stream>>>(Snode, batch, bc, (float*)d_out, N);
}

// Round 15
// 337.453 us; speedup vs baseline: 1.6983x; 1.0071x over previous
//
#include <hip/hip_runtime.h>

typedef unsigned short ushort_t;
typedef unsigned int uint_t;
typedef unsigned char u8_t;

typedef __bf16 bf16x8 __attribute__((ext_vector_type(8)));
typedef _Float16 f16x8 __attribute__((ext_vector_type(8)));
typedef float f32x4 __attribute__((ext_vector_type(4)));
typedef uint_t uint32x4 __attribute__((ext_vector_type(4)));
typedef uint_t uint32x2 __attribute__((ext_vector_type(2)));
typedef _Float16 h2 __attribute__((ext_vector_type(2)));

#define EPB 5120     // edges per build chunk (NBLK=625 -> 2.4 blocks/CU in p1/p3)
#define NSH 9        // bucket = dst >> NSH (512 nodes/bucket, B=196)
                     // R11 lesson: NSH=7 gave 26B scatter runs -> 5.7x write amp.
#define MSK 511      // (1<<NSH)-1
#define BPAD 4104    // per-bucket adj pad slack: 8*512 worst case + 8 align (mult of 8)

// R13 lesson (atomics, pole 2): fusing pool as atomicAdd(&gsum[batch[node]]) took
// agg_pool 60->285us. batch is SORTED, so all resident blocks hit the same 1-2 lines
// with device-scope RMW across 8 non-coherent XCDs -> same-line serialization.
// (R9 was the other pole: scattered 4B atomics -> 15x partial-line write amp.)
// Pool therefore stays a deterministic per-node store + tiny separate kernel.

// ---------- bf16 helpers (RNE fp32->bf16; bit-shift bf16->fp32) ----------
__device__ __forceinline__ float b2f(ushort_t u) {
    union { uint_t ui; float f; } c; c.ui = ((uint_t)u) << 16; return c.f;
}
__device__ __forceinline__ ushort_t f2b(float f) {
    union { float f; uint_t ui; } c; c.f = f;
    uint_t u = c.ui;
    uint_t r = (u + 0x7fffu + ((u >> 16) & 1u)) >> 16;
    return (ushort_t)r;
}
// fp32 -> fp8 e5m2 (RNE via f16; e5m2 = top byte of f16)
__device__ __forceinline__ u8_t f2e5(float x) {
    ushort_t h = __builtin_bit_cast(ushort_t, (_Float16)x);
    uint_t r = ((uint_t)h + 0x7Fu + ((h >> 8) & 1u)) >> 8;
    return (u8_t)r;
}
// unpack dword of 4 e5m2 bytes into 2 packed-f16 pairs and accumulate
// (e5m2<<8 is an EXACT f16: same exponent bias/width, mantissa zero-extended)
__device__ __forceinline__ void upk_add(uint_t d, h2* acc) {
    uint_t A = __builtin_amdgcn_perm(0u, d, 0x010C000Cu);  // (b0<<8, b1<<8) = two f16
    uint_t B = __builtin_amdgcn_perm(0u, d, 0x030C020Cu);  // (b2<<8, b3<<8)
    acc[0] += __builtin_bit_cast(h2, A);
    acc[1] += __builtin_bit_cast(h2, B);
}

// ---------- P1: per-chunk bucket histogram (LDS atomics only) + weight transpose ----------
// extra blocks: [NBLK, NBLK+128) transpose W1 (bf16) / W2 (f16);
// block NBLK+128 zeroes h8 row N.
__global__ __launch_bounds__(256) void p1_hist(const int* __restrict__ dst,
                                               int* __restrict__ H,
                                               const float* __restrict__ W1,
                                               const float* __restrict__ W2,
                                               ushort_t* __restrict__ W1t,
                                               ushort_t* __restrict__ W2t,
                                               u8_t* __restrict__ h8z,
                                               int E, int NBLK, int B, int N) {
    int t = threadIdx.x, c = blockIdx.x;
    if (c >= NBLK + 128) {                 // zero h8 pad row
        if (t < 32) ((uint_t*)h8z)[(size_t)N * 32 + t] = 0u;
        return;
    }
    if (c >= NBLK) {
        int idx = (c - NBLK) * 256 + t;   // 0..32767
        int sel = idx >> 14;
        int i = idx & 16383;
        int k = i >> 7, nn = i & 127;
        if (sel) {  // W2 -> f16 bits (layer-2 GEMM uses f16 MFMA vs fp8 A-operand)
            W2t[nn * 128 + k] = __builtin_bit_cast(ushort_t, (_Float16)W2[k * 128 + nn]);
        } else {    // W1 -> bf16 bits
            W1t[nn * 128 + k] = f2b(W1[k * 128 + nn]);
        }
        return;
    }
    __shared__ int hist[256];
    if (t < 256) hist[t] = 0;
    __syncthreads();
    int base = c * EPB;
    int lim = min(E - base, EPB);
    for (int i = t; i < lim; i += 256)
        atomicAdd(&hist[dst[base + i] >> NSH], 1);
    __syncthreads();
    if (t < B) H[t * NBLK + c] = hist[t];
}

// ---------- scan: per-256-chunk sums ----------
__global__ __launch_bounds__(256) void reduce256(const int* __restrict__ in,
                                                 int* __restrict__ bsums, int n) {
    __shared__ int s[256];
    int t = threadIdx.x, g = blockIdx.x * 256 + t;
    s[t] = (g < n) ? in[g] : 0;
    __syncthreads();
    for (int o = 128; o > 0; o >>= 1) {
        if (t < o) s[t] += s[t + o];
        __syncthreads();
    }
    if (t == 0) bsums[blockIdx.x] = s[0];
}

// ---------- scan: single-block exclusive scan (n <= 512) ----------
__global__ __launch_bounds__(512) void scan_small(const int* __restrict__ in,
                                                  int* __restrict__ outEx, int n) {
    __shared__ int s[512];
    int t = threadIdx.x;
    int v = (t < n) ? in[t] : 0;
    s[t] = v;
    __syncthreads();
    for (int o = 1; o < 512; o <<= 1) {
        int x = 0;
        if (t >= o) x = s[t - o];
        __syncthreads();
        s[t] += x;
        __syncthreads();
    }
    if (t < n) outEx[t] = s[t] - v;
}

// ---------- scan: per-chunk exclusive scan + chunk offset ----------
__global__ __launch_bounds__(256) void scan256ex(const int* __restrict__ in,
                                                 const int* __restrict__ boffs,
                                                 int* __restrict__ outEx, int n) {
    __shared__ int s[256];
    int t = threadIdx.x, g = blockIdx.x * 256 + t;
    int v = (g < n) ? in[g] : 0;
    s[t] = v;
    __syncthreads();
    for (int o = 1; o < 256; o <<= 1) {
        int x = 0;
        if (t >= o) x = s[t - o];
        __syncthreads();
        s[t] += x;
        __syncthreads();
    }
    if (g < n) outEx[g] = boffs[blockIdx.x] + s[t] - v;
}

// ---------- P3: partition scatter by dst-bucket (LDS rank) ----------
__global__ __launch_bounds__(256) void p3_scatter(const int* __restrict__ src,
                                                  const int* __restrict__ dst,
                                                  const int* __restrict__ Hex,
                                                  uint_t* __restrict__ packed,
                                                  int E, int NBLK, int B) {
    __shared__ int offsL[256];
    __shared__ int cur[256];
    int t = threadIdx.x, c = blockIdx.x;
    if (t < B) {
        offsL[t] = Hex[t * NBLK + c];
        cur[t] = 0;
    }
    __syncthreads();
    int base = c * EPB;
    int lim = min(E - base, EPB);
    for (int i = t; i < lim; i += 256) {
        int d = dst[base + i];
        int s = src[base + i];
        int b = d >> NSH;
        int r = atomicAdd(&cur[b], 1);
        packed[offsL[b] + r] = ((uint_t)s << NSH) | (uint_t)(d & MSK);
    }
}

// ---------- P4: per-bucket padded CSR build (512 nodes/bucket, streamed twice) ------
// R15: 1024 threads/block (was 512). B=196 blocks means <1 block/CU, so per-block
// wave count is the only occupancy lever: 16 waves = 4/SIMD (was 2/SIMD = 25%).
// Count/scatter loops stride 1024; the 512-entry scan + node init use threads 0-511.
__global__ __launch_bounds__(1024) void p4_build(const uint_t* __restrict__ packed,
                                                 const int* __restrict__ Hex,
                                                 int* __restrict__ adj,
                                                 int* __restrict__ offs,
                                                 int* __restrict__ dgr,
                                                 float* __restrict__ dinv,
                                                 int E, int N, int NBLK, int B) {
    __shared__ int dcnt[512], loc[512], cur[512], sps[512];
    int t = threadIdx.x, b = blockIdx.x;
    int bs = Hex[b * NBLK];
    int be = (b + 1 < B) ? Hex[(b + 1) * NBLK] : E;
    int m = be - bs;
    if (t < 512) dcnt[t] = 0;
    __syncthreads();
    for (int i = t; i < m; i += 1024)
        atomicAdd(&dcnt[packed[bs + i] & MSK], 1);
    __syncthreads();
    int d = 0, pd = 0;
    if (t < 512) {
        d = dcnt[t];
        pd = (d + 8) & ~7;   // (deg + 1 self) rounded up to 8
        sps[t] = pd;
    }
    __syncthreads();
    for (int o = 1; o < 512; o <<= 1) {   // inclusive scan over 512 padded degrees
        int x = 0;
        if (t < 512 && t >= o) x = sps[t - o];
        __syncthreads();
        if (t < 512) sps[t] += x;
        __syncthreads();
    }
    int bsp = ((bs + 7) & ~7) + b * BPAD;   // aligned padded bucket base
    if (t < 512) {
        int ex = sps[t] - pd;
        int node = b * 512 + t;
        if (node < N) {
            int nbase = bsp + ex;
            offs[node] = nbase;
            dgr[node]  = pd;
            dinv[node] = rsqrtf((float)(d + 1));
            adj[nbase] = node;                        // self-loop first
            for (int i = d + 1; i < pd; ++i)
                adj[nbase + i] = N;                   // zero-row pads
        }
        loc[t] = ex + 1;   // neighbors start after the self entry
        cur[t] = 0;
    }
    __syncthreads();
    for (int i = t; i < m; i += 1024) {
        uint_t p = packed[bs + i];
        int l = p & MSK;
        int r = atomicAdd(&cur[l], 1);
        adj[bsp + loc[l] + r] = (int)(p >> NSH);
    }
}

// ---------- GEMM layer-2 (fp8 e5m2 A in, f16 MFMA): H8 = e5m2((A@W2)*dinv) ----------
// A bytes <<8 are exact f16; B = W2t stored as f16 (MORE precise than the old bf16).
__global__ __launch_bounds__(256, 4) void gemm_scale(const u8_t* __restrict__ Xin8,
                                                     const ushort_t* __restrict__ Wt,
                                                     const float* __restrict__ dinv,
                                                     u8_t* __restrict__ Hout8, int n) {
    __shared__ ushort_t lds[128 * 136];
    int tid = threadIdx.x;
    for (int i = tid; i < 128 * 16; i += 256) {
        int r = i >> 4, c8 = (i & 15) << 3;
        *(uint32x4*)(lds + r * 136 + c8) = *(const uint32x4*)(Wt + r * 128 + c8);
    }
    __syncthreads();
    int lane = tid & 63, wave = tid >> 6;
    int m = lane & 15, q = lane >> 4;
    int row0 = blockIdx.x * 64 + wave * 16;
    int ar = row0 + m;
    if (ar > n - 1) ar = n - 1;
    f16x8 a[4];
#pragma unroll
    for (int ks = 0; ks < 4; ++ks) {
        uint32x2 dv8 = *(const uint32x2*)(Xin8 + (size_t)ar * 128 + ks * 32 + q * 8);
        uint_t tw[4];
        tw[0] = __builtin_amdgcn_perm(0u, dv8[0], 0x010C000Cu);  // (b0,b1) as f16
        tw[1] = __builtin_amdgcn_perm(0u, dv8[0], 0x030C020Cu);  // (b2,b3)
        tw[2] = __builtin_amdgcn_perm(0u, dv8[1], 0x010C000Cu);  // (b4,b5)
        tw[3] = __builtin_amdgcn_perm(0u, dv8[1], 0x030C020Cu);  // (b6,b7)
        a[ks] = __builtin_bit_cast(f16x8, *(uint32x4*)tw);
    }
    f32x4 acc[8];
    f32x4 zero = {0.f, 0.f, 0.f, 0.f};
#pragma unroll
    for (int nt = 0; nt < 8; ++nt) acc[nt] = zero;
#pragma unroll
    for (int nt = 0; nt < 8; ++nt) {
#pragma unroll
        for (int ks = 0; ks < 4; ++ks) {
            f16x8 b = __builtin_bit_cast(f16x8,
                *(const uint32x4*)(lds + (nt * 16 + m) * 136 + ks * 32 + q * 8));
            acc[nt] = __builtin_amdgcn_mfma_f32_16x16x32_f16(a[ks], b, acc[nt], 0, 0, 0);
        }
    }
    float dv[4];
#pragma unroll
    for (int r = 0; r < 4; ++r) {
        int gr = row0 + q * 4 + r;
        dv[r] = (gr < n) ? dinv[gr] : 0.f;
    }
#pragma unroll
    for (int nt = 0; nt < 8; ++nt) {
#pragma unroll
        for (int r = 0; r < 4; ++r) {
            int gr = row0 + q * 4 + r;
            if (gr < n)
                Hout8[(size_t)gr * 128 + nt * 16 + m] = f2e5(acc[nt][r] * dv[r]);
        }
    }
}

// ---------- GEMM layer-1 variant: fp32 A input, bf16 MFMA ----------
__global__ __launch_bounds__(256, 4) void gemm_scale_f32(const float* __restrict__ Xf,
                                                         const ushort_t* __restrict__ Wt,
                                                         const float* __restrict__ dinv,
                                                         u8_t* __restrict__ Hout8, int n) {
    __shared__ ushort_t lds[128 * 136];
    int tid = threadIdx.x;
    for (int i = tid; i < 128 * 16; i += 256) {
        int r = i >> 4, c8 = (i & 15) << 3;
        *(uint32x4*)(lds + r * 136 + c8) = *(const uint32x4*)(Wt + r * 128 + c8);
    }
    __syncthreads();
    int lane = tid & 63, wave = tid >> 6;
    int m = lane & 15, q = lane >> 4;
    int row0 = blockIdx.x * 64 + wave * 16;
    int ar = row0 + m;
    if (ar > n - 1) ar = n - 1;
    bf16x8 a[4];
#pragma unroll
    for (int ks = 0; ks < 4; ++ks) {
        const float* p = Xf + (size_t)ar * 128 + ks * 32 + q * 8;
        f32x4 lo = *(const f32x4*)p;
        f32x4 hi = *(const f32x4*)(p + 4);
        ushort_t t[8];
        t[0] = f2b(lo[0]); t[1] = f2b(lo[1]); t[2] = f2b(lo[2]); t[3] = f2b(lo[3]);
        t[4] = f2b(hi[0]); t[5] = f2b(hi[1]); t[6] = f2b(hi[2]); t[7] = f2b(hi[3]);
        a[ks] = __builtin_bit_cast(bf16x8, *(uint32x4*)t);
    }
    f32x4 acc[8];
    f32x4 zero = {0.f, 0.f, 0.f, 0.f};
#pragma unroll
    for (int nt = 0; nt < 8; ++nt) acc[nt] = zero;
#pragma unroll
    for (int nt = 0; nt < 8; ++nt) {
#pragma unroll
        for (int ks = 0; ks < 4; ++ks) {
            bf16x8 b = __builtin_bit_cast(bf16x8,
                *(const uint32x4*)(lds + (nt * 16 + m) * 136 + ks * 32 + q * 8));
            acc[nt] = __builtin_amdgcn_mfma_f32_16x16x32_bf16(a[ks], b, acc[nt], 0, 0, 0);
        }
    }
    float dv[4];
#pragma unroll
    for (int r = 0; r < 4; ++r) {
        int gr = row0 + q * 4 + r;
        dv[r] = (gr < n) ? dinv[gr] : 0.f;
    }
#pragma unroll
    for (int nt = 0; nt < 8; ++nt) {
#pragma unroll
        for (int r = 0; r < 4; ++r) {
            int gr = row0 + q * 4 + r;
            if (gr < n)
                Hout8[(size_t)gr * 128 + nt * 16 + m] = f2e5(acc[nt][r] * dv[r]);
        }
    }
}

// gather+accumulate over the PADDED CSR (R6's proven memory pattern, unchanged).
__device__ __forceinline__ void agg_core(const u8_t* __restrict__ Hs8,
                                         const int* __restrict__ adj,
                                         int beg, int pd, int g, uint_t colb,
                                         h2* acc) {
    int e = 0;
    for (; e + 16 <= pd; e += 16) {
        const int4 sv = *(const int4*)(adj + beg + e + g * 4);
        uint_t o0 = ((uint_t)sv.x << 7) | colb;
        uint_t o1 = ((uint_t)sv.y << 7) | colb;
        uint_t o2 = ((uint_t)sv.z << 7) | colb;
        uint_t o3 = ((uint_t)sv.w << 7) | colb;
        uint32x2 w0 = *(const uint32x2*)(Hs8 + o0);
        uint32x2 w1 = *(const uint32x2*)(Hs8 + o1);
        uint32x2 w2 = *(const uint32x2*)(Hs8 + o2);
        uint32x2 w3 = *(const uint32x2*)(Hs8 + o3);
        upk_add(w0[0], acc); upk_add(w0[1], acc + 2);
        upk_add(w1[0], acc); upk_add(w1[1], acc + 2);
        upk_add(w2[0], acc); upk_add(w2[1], acc + 2);
        upk_add(w3[0], acc); upk_add(w3[1], acc + 2);
    }
    if (e < pd) {   // 8-edge tail (pd is a multiple of 8; condition is wave-uniform)
        const int2 sv = *(const int2*)(adj + beg + e + g * 2);
        uint_t o0 = ((uint_t)sv.x << 7) | colb;
        uint_t o1 = ((uint_t)sv.y << 7) | colb;
        uint32x2 w0 = *(const uint32x2*)(Hs8 + o0);
        uint32x2 w1 = *(const uint32x2*)(Hs8 + o1);
        upk_add(w0[0], acc); upk_add(w0[1], acc + 2);
        upk_add(w1[0], acc); upk_add(w1[1], acc + 2);
    }
}

// slot-reduce: sum acc over the 4 edge slots (lane bits 4..5); l16 bits untouched
__device__ __forceinline__ void slot_reduce(h2* acc) {
#pragma unroll
    for (int k = 0; k < 4; ++k) {
        uint_t v = __builtin_bit_cast(uint_t, acc[k]);
        acc[k] += __builtin_bit_cast(h2, (uint_t)__shfl_xor(v, 16, 64));
        v = __builtin_bit_cast(uint_t, acc[k]);
        acc[k] += __builtin_bit_cast(h2, (uint_t)__shfl_xor(v, 32, 64));
    }
}

// ---------- aggregation (layer 1): Out8 = e5m2(relu(dinv*(sum Hs8) + b)) ----------
// fp8 output (12.8MB vs bf16's 25.6MB); layer-2 GEMM consumes fp8 via exact f16
// expansion, so the only cost is a quantization that happened post-GEMM anyway.
__global__ __launch_bounds__(256, 4) void agg_kernel(const u8_t* __restrict__ Hs8,
                                                     const int* __restrict__ adj,
                                                     const int* __restrict__ offs,
                                                     const int* __restrict__ dgr,
                                                     const float* __restrict__ dinv,
                                                     const float* __restrict__ bias,
                                                     u8_t* __restrict__ Out8, int n) {
    int node = blockIdx.x * 4 + (threadIdx.x >> 6);
    if (node >= n) return;
    int lane = threadIdx.x & 63;
    int g = lane >> 4;           // edge slot 0..3
    int l16 = lane & 15;         // column group: 8 cols each
    uint_t colb = (uint_t)l16 * 8;
    const int beg = offs[node];
    const int pd  = dgr[node];
    h2 acc[4];
    h2 hz = {(_Float16)0.f, (_Float16)0.f};
#pragma unroll
    for (int k = 0; k < 4; ++k) acc[k] = hz;
    agg_core(Hs8, adj, beg, pd, g, colb, acc);
    slot_reduce(acc);
    if (g == 0) {
        float di = dinv[node];
        u8_t o[8];
#pragma unroll
        for (int k = 0; k < 4; ++k) {
            float f0 = (float)acc[k][0];
            float f1 = (float)acc[k][1];
            o[2 * k]     = f2e5(fmaxf(di * f0 + bias[colb + 2 * k], 0.f));
            o[2 * k + 1] = f2e5(fmaxf(di * f1 + bias[colb + 2 * k + 1], 0.f));
        }
        *(uint32x2*)(Out8 + (size_t)node * 128 + colb) = *(uint32x2*)o;
    }
}

// ---------- aggregation (layer 2) + classifier dot: S[i] = relu(...) . Wc ----------
// Deterministic per-node store (R13 lesson: NO atomic pool accumulate).
__global__ __launch_bounds__(256, 4) void agg_pool_kernel(const u8_t* __restrict__ Hs8,
                                                          const int* __restrict__ adj,
                                                          const int* __restrict__ offs,
                                                          const int* __restrict__ dgr,
                                                          const float* __restrict__ dinv,
                                                          const float* __restrict__ bias,
                                                          const float* __restrict__ Wc,
                                                          float* __restrict__ Sout, int n) {
    int node = blockIdx.x * 4 + (threadIdx.x >> 6);
    if (node >= n) return;
    int lane = threadIdx.x & 63;
    int g = lane >> 4;
    int l16 = lane & 15;
    uint_t colb = (uint_t)l16 * 8;
    const int beg = offs[node];
    const int pd  = dgr[node];
    h2 acc[4];
    h2 hz = {(_Float16)0.f, (_Float16)0.f};
#pragma unroll
    for (int k = 0; k < 4; ++k) acc[k] = hz;
    agg_core(Hs8, adj, beg, pd, g, colb, acc);
    slot_reduce(acc);
    // classifier dot in-register: g==0 lanes hold 8 full cols each
    float local = 0.f;
    float di = dinv[node];
#pragma unroll
    for (int k = 0; k < 4; ++k) {
        float f0 = fmaxf(di * (float)acc[k][0] + bias[colb + 2 * k], 0.f);
        float f1 = fmaxf(di * (float)acc[k][1] + bias[colb + 2 * k + 1], 0.f);
        local += f0 * Wc[colb + 2 * k] + f1 * Wc[colb + 2 * k + 1];
    }
    // reduce across l16 (lane bits 0..3); g bits untouched so g==0 lanes stay pure
    local += __shfl_xor(local, 1, 64);
    local += __shfl_xor(local, 2, 64);
    local += __shfl_xor(local, 4, 64);
    local += __shfl_xor(local, 8, 64);
    if (lane == 0) Sout[node] = local;
}

// ---------- pooling: out[g] = sigmoid(mean_{i in g} S[i] + bc) ----------
__global__ __launch_bounds__(256) void pool2_kernel(const float* __restrict__ S,
                                                    const int* __restrict__ batch,
                                                    const float* __restrict__ bc,
                                                    float* __restrict__ out, int n) {
    int g = blockIdx.x;
    int t = threadIdx.x;
    int lo = 0, hi = n;
    while (lo < hi) { int mid = (lo + hi) >> 1; if (batch[mid] < g) lo = mid + 1; else hi = mid; }
    int start = lo;
    hi = n;
    while (lo < hi) { int mid = (lo + hi) >> 1; if (batch[mid] < g + 1) lo = mid + 1; else hi = mid; }
    int stop = lo;
    float s = 0.f;
    for (int i = start + t; i < stop; i += 256) s += S[i];
    __shared__ float red[256];
    red[t] = s;
    __syncthreads();
    for (int o = 128; o > 0; o >>= 1) {
        if (t < o) red[t] += red[t + o];
        __syncthreads();
    }
    if (t == 0) {
        int cg = stop - start;
        float z = red[0] / (float)(cg > 0 ? cg : 1) + bc[0];
        out[g] = 1.f / (1.f + expf(-z));
    }
}

extern "C" void kernel_launch(void* const* d_in, const int* in_sizes, int n_in,
                              void* d_out, int out_size, void* d_ws, size_t ws_size,
                              hipStream_t stream) {
    const float* X     = (const float*)d_in[0];
    const int* ei      = (const int*)d_in[1];
    const int* batch   = (const int*)d_in[2];
    const float* W1    = (const float*)d_in[3];
    const float* b1    = (const float*)d_in[4];
    const float* W2    = (const float*)d_in[5];
    const float* b2    = (const float*)d_in[6];
    const float* Wc    = (const float*)d_in[7];
    const float* bc    = (const float*)d_in[8];

    const int N = in_sizes[2];
    const int E = in_sizes[1] / 2;
    const int G = out_size;
    const int* srcv = ei;
    const int* dstv = ei + E;

    const int NBLK = (E + EPB - 1) / EPB;      // edge chunks (~625)
    const int B    = (N + MSK) >> NSH;         // dst buckets (~196)
    const int n0   = B * NBLK;                 // histogram matrix (~122.5K)
    const int g1   = (n0 + 255) / 256;         // <= 512 by construction (~479)

    char* p = (char*)d_ws;
    auto alloc = [&](size_t bytes) -> void* {
        void* r = (void*)p;
        p += (bytes + 255) & ~(size_t)255;
        return r;
    };
    int* H         = (int*)alloc((size_t)n0 * 4);
    int* Hex       = (int*)alloc((size_t)n0 * 4);
    int* S1        = (int*)alloc((size_t)g1 * 4);
    int* S1ex      = (int*)alloc((size_t)g1 * 4);
    uint_t* packed = (uint_t*)alloc((size_t)E * 4);
    int* adj       = (int*)alloc(((size_t)E + (size_t)B * BPAD + 4224) * 4); // padded CSR
    int* offs      = (int*)alloc(((size_t)N + 1) * 4);
    int* dgr       = (int*)alloc((size_t)N * 4);
    float* dinv    = (float*)alloc((size_t)N * 4);
    ushort_t* W1t  = (ushort_t*)alloc(16384 * 2);
    ushort_t* W2t  = (ushort_t*)alloc(16384 * 2);
    u8_t* h8       = (u8_t*)alloc(((size_t)N + 1) * 128);   // gather table (+ zero row)
    u8_t* h8b      = (u8_t*)alloc((size_t)N * 128);         // layer-1 out / layer-2 GEMM in
    float* Snode   = (float*)alloc((size_t)N * 4);

    // ---- CSR build (LDS atomics only; 6 dispatches, 2-level scan) ----
    p1_hist<<<NBLK + 129, 256, 0, stream>>>(dstv, H, W1, W2, W1t, W2t, h8,
                                            E, NBLK, B, N);
    reduce256<<<g1, 256, 0, stream>>>(H, S1, n0);
    scan_small<<<1, 512, 0, stream>>>(S1, S1ex, g1);
    scan256ex<<<g1, 256, 0, stream>>>(H, S1ex, Hex, n0);
    p3_scatter<<<NBLK, 256, 0, stream>>>(srcv, dstv, Hex, packed, E, NBLK, B);
    p4_build<<<B, 1024, 0, stream>>>(packed, Hex, adj, offs, dgr, dinv, E, N, NBLK, B);

    const int GB = (N + 63) / 64;
    const int AB = (N + 3) / 4;
    // layer 1 (cast fused into GEMM; fp8 e5m2 gather table)
    gemm_scale_f32<<<GB, 256, 0, stream>>>(X, W1t, dinv, h8, N);
    agg_kernel<<<AB, 256, 0, stream>>>(h8, adj, offs, dgr, dinv, b1, h8b, N);
    // layer 2 (fp8 A-input f16-MFMA GEMM; classifier dot fused into agg epilogue)
    gemm_scale<<<GB, 256, 0, stream>>>(h8b, W2t, dinv, h8, N);
    agg_pool_kernel<<<AB, 256, 0, stream>>>(h8, adj, offs, dgr, dinv, b2, Wc, Snode, N);
    // pool + sigmoid over per-node scalars
    pool2_kernel<<<G, 256, 0, stream>>>(Snode, batch, bc, (float*)d_out, N);
}